// Round 4
// baseline (94.609 us; speedup 1.0000x reference)
//
#include <hip/hip_runtime.h>
#include <math.h>

#define MLEN 4096
#define RANK 16
#define NROWS 1024
#define TWO_PI 6.2831853071795864769f

// Module-static global scratch for the FFT'd H (16 x 4096 complex = 512 KB).
// No hipMalloc, graph-capture safe; fully rewritten every kernel_launch call.
__device__ float2 g_Hft[RANK * MLEN];

// stable softplus: max(x,0) + log1p(exp(-|x|))
__device__ __forceinline__ float softplus_f(float x) {
    return fmaxf(x, 0.0f) + log1pf(__expf(-fabsf(x)));
}

// In-place radix-2 DIT FFT of softplus(H[row,:]) per block. LDS = 4096 float2 = 32 KB.
__global__ __launch_bounds__(1024) void fft_rows_kernel(const float* __restrict__ H) {
    __shared__ float2 buf[MLEN];
    const int row = blockIdx.x;
    const int tid = threadIdx.x;
    const float* h = H + row * MLEN;

    // bit-reversed load (12-bit reversal), imag = 0
    for (int i = tid; i < MLEN; i += 1024) {
        int j = (int)(__brev((unsigned)i) >> 20);
        buf[j] = make_float2(softplus_f(h[i]), 0.0f);
    }
    __syncthreads();

    #pragma unroll
    for (int s = 0; s < 12; ++s) {
        const int half = 1 << s;
        const float inv_len = 1.0f / (float)(half << 1);   // exact pow2
        for (int t = tid; t < MLEN / 2; t += 1024) {
            const int pos = t & (half - 1);
            const int i0  = ((t >> s) << (s + 1)) + pos;
            const int i1  = i0 + half;
            // w = exp(-2*pi*i * pos/len) = (c, -sn)
            float sn, c;
            __sincosf(TWO_PI * ((float)pos * inv_len), &sn, &c);
            const float2 a = buf[i0];
            const float2 b = buf[i1];
            const float vre = c * b.x + sn * b.y;
            const float vim = c * b.y - sn * b.x;
            buf[i0] = make_float2(a.x + vre, a.y + vim);
            buf[i1] = make_float2(a.x - vre, a.y - vim);
        }
        __syncthreads();
    }

    for (int i = tid; i < MLEN; i += 1024) {
        g_Hft[row * MLEN + i] = buf[i];
    }
}

// V[n,m] = sum_d softplus(W[n,d]) * exp(-2pi*i * tau[n,d]*m/M) * Hft[d,m]
// Block: 256 threads = 256 consecutive m; 16 n per block.
// MODE 0: out_size == N*M      -> store real(V) only (harness compares float32 per complex elem)
// MODE 1: out_size == 2*N*M    -> store interleaved (re, im)
// MODE 2: unknown              -> guarded interleaved
template <int MODE>
__global__ __launch_bounds__(256) void shiftnmf_mix_kernel(const float* __restrict__ W,
                                                           const float* __restrict__ tau,
                                                           float* __restrict__ out,
                                                           int out_size_floats) {
    __shared__ float sw_s[256];   // [ln][d]
    __shared__ float tau_s[256];

    const int tid = threadIdx.x;
    const int m   = blockIdx.x * 256 + tid;
    const int n0  = blockIdx.y * 16;

    // 256 threads cover exactly 16 n x 16 d; W rows are contiguous (N, RANK)
    sw_s[tid]  = softplus_f(W[n0 * RANK + tid]);
    tau_s[tid] = tau[n0 * RANK + tid];
    __syncthreads();

    // per-thread Hft fragment: 16 x float2 = 32 VGPRs, reused across 16 n
    float2 h[RANK];
    #pragma unroll
    for (int d = 0; d < RANK; ++d) h[d] = g_Hft[d * MLEN + m];

    const float fm = (float)m * (1.0f / (float)MLEN);

    #pragma unroll 1
    for (int ln = 0; ln < 16; ++ln) {
        float sw[RANK], tv[RANK];
        #pragma unroll
        for (int d = 0; d < RANK; ++d) {
            sw[d] = sw_s[ln * RANK + d];
            tv[d] = tau_s[ln * RANK + d];
        }

        float ar = 0.0f, ai = 0.0f;
        #pragma unroll
        for (int d = 0; d < RANK; ++d) {
            // theta = 2*pi * (tau*f), tau*f in [0,1)
            float s, c;
            __sincosf(TWO_PI * (tv[d] * fm), &s, &c);
            // e^{-i theta} * Hft = (c*hx + s*hy, c*hy - s*hx)
            ar = fmaf(sw[d], fmaf(s, h[d].y, c * h[d].x), ar);
            if (MODE != 0) {
                ai = fmaf(sw[d], fmaf(c, h[d].y, -s * h[d].x), ai);
            }
        }
        const int nm = (n0 + ln) * MLEN + m;
        if (MODE == 0) {
            out[nm] = ar;                      // real part only, 1 float per element
        } else if (MODE == 1) {
            out[2 * nm]     = ar;
            out[2 * nm + 1] = ai;
        } else {
            const long long fi = 2LL * nm;
            if (fi + 1 < (long long)out_size_floats) {
                out[fi]     = ar;
                out[fi + 1] = ai;
            }
        }
    }
}

extern "C" void kernel_launch(void* const* d_in, const int* in_sizes, int n_in,
                              void* d_out, int out_size, void* d_ws, size_t ws_size,
                              hipStream_t stream) {
    const float* W   = (const float*)d_in[0];   // (1024, 16)
    const float* H   = (const float*)d_in[1];   // (16, 4096)
    const float* tau = (const float*)d_in[2];   // (1024, 16)
    float* out = (float*)d_out;
    (void)d_ws; (void)ws_size; (void)in_sizes; (void)n_in;

    fft_rows_kernel<<<dim3(RANK), dim3(1024), 0, stream>>>(H);

    const dim3 grid(MLEN / 256, NROWS / 16);
    if (out_size == NROWS * MLEN) {
        shiftnmf_mix_kernel<0><<<grid, dim3(256), 0, stream>>>(W, tau, out, out_size);
    } else if (out_size == 2 * NROWS * MLEN) {
        shiftnmf_mix_kernel<1><<<grid, dim3(256), 0, stream>>>(W, tau, out, out_size);
    } else {
        shiftnmf_mix_kernel<2><<<grid, dim3(256), 0, stream>>>(W, tau, out, out_size);
    }
}

// Round 5
// 88.052 us; speedup vs baseline: 1.0745x; 1.0745x over previous
//
#include <hip/hip_runtime.h>
#include <math.h>

#define MLEN 4096
#define RANK 16
#define NROWS 1024

// Module-static global scratch for the FFT'd H (16 x 4096 complex = 512 KB).
// No hipMalloc, graph-capture safe; fully rewritten every kernel_launch call.
__device__ float2 g_Hft[RANK * MLEN];

// stable softplus: max(x,0) + log1p(exp(-|x|))
__device__ __forceinline__ float softplus_f(float x) {
    return fmaxf(x, 0.0f) + log1pf(__expf(-fabsf(x)));
}

// In-place radix-2 DIT FFT of softplus(H[row,:]) per block. LDS = 4096 float2 = 32 KB.
// Twiddles via hardware v_sin/v_cos: input in REVOLUTIONS, r = pos/len in [0,0.5).
__global__ __launch_bounds__(1024) void fft_rows_kernel(const float* __restrict__ H) {
    __shared__ float2 buf[MLEN];
    const int row = blockIdx.x;
    const int tid = threadIdx.x;
    const float* h = H + row * MLEN;

    // bit-reversed load (12-bit reversal), imag = 0
    for (int i = tid; i < MLEN; i += 1024) {
        int j = (int)(__brev((unsigned)i) >> 20);
        buf[j] = make_float2(softplus_f(h[i]), 0.0f);
    }
    __syncthreads();

    #pragma unroll
    for (int s = 0; s < 12; ++s) {
        const int half = 1 << s;
        const float inv_len = 1.0f / (float)(half << 1);   // exact pow2
        for (int t = tid; t < MLEN / 2; t += 1024) {
            const int pos = t & (half - 1);
            const int i0  = ((t >> s) << (s + 1)) + pos;
            const int i1  = i0 + half;
            // w = exp(-2*pi*i * pos/len) = (c, -sn); v_sin/v_cos take revolutions
            const float r  = (float)pos * inv_len;
            const float c  = __builtin_amdgcn_cosf(r);
            const float sn = __builtin_amdgcn_sinf(r);
            const float2 a = buf[i0];
            const float2 b = buf[i1];
            const float vre = c * b.x + sn * b.y;
            const float vim = c * b.y - sn * b.x;
            buf[i0] = make_float2(a.x + vre, a.y + vim);
            buf[i1] = make_float2(a.x - vre, a.y - vim);
        }
        __syncthreads();
    }

    for (int i = tid; i < MLEN; i += 1024) {
        g_Hft[row * MLEN + i] = buf[i];
    }
}

// V[n,m] = sum_d softplus(W[n,d]) * exp(-2pi*i * tau[n,d]*m/M) * Hft[d,m]
// Block: 256 threads = 256 consecutive m; 16 n per block.
// MODE 0: out_size == N*M   -> store real(V) only
// MODE 1: out_size == 2*N*M -> store interleaved (re, im)
// MODE 2: unknown           -> guarded interleaved
template <int MODE>
__global__ __launch_bounds__(256) void shiftnmf_mix_kernel(const float* __restrict__ W,
                                                           const float* __restrict__ tau,
                                                           float* __restrict__ out,
                                                           int out_size_floats) {
    __shared__ __align__(16) float sw_s[256];   // [ln][d]
    __shared__ __align__(16) float tau_s[256];

    const int tid = threadIdx.x;
    const int m   = blockIdx.x * 256 + tid;
    const int n0  = blockIdx.y * 16;

    // 256 threads cover exactly 16 n x 16 d; W rows are contiguous (N, RANK)
    sw_s[tid]  = softplus_f(W[n0 * RANK + tid]);
    tau_s[tid] = tau[n0 * RANK + tid];
    __syncthreads();

    // per-thread Hft fragment: 16 x float2 = 32 VGPRs, reused across 16 n
    float2 h[RANK];
    #pragma unroll
    for (int d = 0; d < RANK; ++d) h[d] = g_Hft[d * MLEN + m];

    const float fm = (float)m * (1.0f / (float)MLEN);

    #pragma unroll 1
    for (int ln = 0; ln < 16; ++ln) {
        // uniform-address LDS float4 broadcasts (conflict-free, 16B-aligned)
        const float4* swv = (const float4*)(sw_s  + ln * RANK);
        const float4* tav = (const float4*)(tau_s + ln * RANK);

        float ar = 0.0f, ai = 0.0f;
        #pragma unroll
        for (int q = 0; q < 4; ++q) {
            const float4 a = swv[q];
            const float4 b = tav[q];
            const float swq[4] = {a.x, a.y, a.z, a.w};
            const float tvq[4] = {b.x, b.y, b.z, b.w};
            #pragma unroll
            for (int j = 0; j < 4; ++j) {
                const int d = 4 * q + j;
                // r = tau*f in [0,1): revolutions — native v_sin/v_cos domain,
                // no range reduction, no 2*pi multiply.
                const float r = tvq[j] * fm;
                const float c = __builtin_amdgcn_cosf(r);
                const float s = __builtin_amdgcn_sinf(r);
                // e^{-2pi i r} * Hft = (c*hx + s*hy, c*hy - s*hx)
                ar = fmaf(swq[j], fmaf(s, h[d].y, c * h[d].x), ar);
                if (MODE != 0) {
                    ai = fmaf(swq[j], fmaf(c, h[d].y, -s * h[d].x), ai);
                }
            }
        }
        const int nm = (n0 + ln) * MLEN + m;
        if (MODE == 0) {
            out[nm] = ar;                      // real part only, 1 float per element
        } else if (MODE == 1) {
            out[2 * nm]     = ar;
            out[2 * nm + 1] = ai;
        } else {
            const long long fi = 2LL * nm;
            if (fi + 1 < (long long)out_size_floats) {
                out[fi]     = ar;
                out[fi + 1] = ai;
            }
        }
    }
}

extern "C" void kernel_launch(void* const* d_in, const int* in_sizes, int n_in,
                              void* d_out, int out_size, void* d_ws, size_t ws_size,
                              hipStream_t stream) {
    const float* W   = (const float*)d_in[0];   // (1024, 16)
    const float* H   = (const float*)d_in[1];   // (16, 4096)
    const float* tau = (const float*)d_in[2];   // (1024, 16)
    float* out = (float*)d_out;
    (void)d_ws; (void)ws_size; (void)in_sizes; (void)n_in;

    fft_rows_kernel<<<dim3(RANK), dim3(1024), 0, stream>>>(H);

    const dim3 grid(MLEN / 256, NROWS / 16);
    if (out_size == NROWS * MLEN) {
        shiftnmf_mix_kernel<0><<<grid, dim3(256), 0, stream>>>(W, tau, out, out_size);
    } else if (out_size == 2 * NROWS * MLEN) {
        shiftnmf_mix_kernel<1><<<grid, dim3(256), 0, stream>>>(W, tau, out, out_size);
    } else {
        shiftnmf_mix_kernel<2><<<grid, dim3(256), 0, stream>>>(W, tau, out, out_size);
    }
}

// Round 6
// 82.913 us; speedup vs baseline: 1.1411x; 1.0620x over previous
//
#include <hip/hip_runtime.h>
#include <math.h>

#define MLEN 4096
#define RANK 16
#define NROWS 1024
#define LNB 8            // n-rows per mix block

// Module-static global scratch for the FFT'd H (16 x 4096 complex = 512 KB).
// No hipMalloc, graph-capture safe; fully rewritten every kernel_launch call.
__device__ float2 g_Hft[RANK * MLEN];

// stable softplus: max(x,0) + log1p(exp(-|x|))
__device__ __forceinline__ float softplus_f(float x) {
    return fmaxf(x, 0.0f) + log1pf(__expf(-fabsf(x)));
}

// Radix-2 DIT FFT of softplus(H[row,:]), two stages fused per pass (radix-4
// dataflow): 6 passes, 1 quad per thread (MLEN/4 = 1024 threads), barrier only
// between passes (quads partition the array -> no intra-pass hazard).
// Twiddles in REVOLUTIONS for hw v_sin/v_cos; w1 = wA^2 via double-angle.
__global__ __launch_bounds__(1024) void fft_rows_kernel(const float* __restrict__ H) {
    __shared__ float2 buf[MLEN];
    const int row = blockIdx.x;
    const int t   = threadIdx.x;
    const float* h = H + row * MLEN;

    for (int i = t; i < MLEN; i += 1024) {
        int j = (int)(__brev((unsigned)i) >> 20);   // 12-bit reversal
        buf[j] = make_float2(softplus_f(h[i]), 0.0f);
    }
    __syncthreads();

    #pragma unroll
    for (int s = 0; s < 12; s += 2) {
        const int h1 = 1 << s;
        const int p  = t & (h1 - 1);
        const int k  = ((t >> s) << (s + 2)) + p;
        const float rA = (float)p * (1.0f / (float)(h1 << 2));  // p/len2
        const float ca = __builtin_amdgcn_cosf(rA);             // wA = (ca,-sa)
        const float sa = __builtin_amdgcn_sinf(rA);
        const float c1 = ca * ca - sa * sa;                     // w1 = wA^2
        const float s1 = 2.0f * ca * sa;

        const float2 a0 = buf[k];
        const float2 a1 = buf[k + h1];
        const float2 a2 = buf[k + 2 * h1];
        const float2 a3 = buf[k + 3 * h1];

        // stage s: pairs (k,k+h1) and (k+2h1,k+3h1), twiddle w1=(c1,-s1)
        const float2 w1a1 = make_float2(c1 * a1.x + s1 * a1.y, c1 * a1.y - s1 * a1.x);
        const float2 w1a3 = make_float2(c1 * a3.x + s1 * a3.y, c1 * a3.y - s1 * a3.x);
        const float2 u0 = make_float2(a0.x + w1a1.x, a0.y + w1a1.y);
        const float2 u1 = make_float2(a0.x - w1a1.x, a0.y - w1a1.y);
        const float2 u2 = make_float2(a2.x + w1a3.x, a2.y + w1a3.y);
        const float2 u3 = make_float2(a2.x - w1a3.x, a2.y - w1a3.y);

        // stage s+1: twiddles wA and wB = -i*wA
        const float2 wAu2 = make_float2(ca * u2.x + sa * u2.y, ca * u2.y - sa * u2.x);
        const float2 v    = make_float2(ca * u3.x + sa * u3.y, ca * u3.y - sa * u3.x);
        const float2 wBu3 = make_float2(v.y, -v.x);            // -i * v

        buf[k]          = make_float2(u0.x + wAu2.x, u0.y + wAu2.y);
        buf[k + h1]     = make_float2(u1.x + wBu3.x, u1.y + wBu3.y);
        buf[k + 2 * h1] = make_float2(u0.x - wAu2.x, u0.y - wAu2.y);
        buf[k + 3 * h1] = make_float2(u1.x - wBu3.x, u1.y - wBu3.y);
        __syncthreads();
    }

    for (int i = t; i < MLEN; i += 1024) {
        g_Hft[row * MLEN + i] = buf[i];
    }
}

// Mirror-pair mix (real-part output): thread owns a in [1,2048]; each (ln,d)
// iteration yields BOTH out[n,a] and out[n,4096-a] via the conjugate-symmetry
//   re(V[n,M-a]) = sum_d qc*tre + qi*tim,  q = sw*e^{-2pi i tau} (per (n,d)),
// where (tre,tim) = e^{-i theta} * Hft[d,a] is shared. a=2048 self-pair is
// consistent (Nyquist bin of real FFT is real). m=0 column done by lane 0.
__global__ __launch_bounds__(256) void mix_mirror_kernel(const float* __restrict__ W,
                                                         const float* __restrict__ tau,
                                                         float* __restrict__ out) {
    __shared__ __align__(16) float sw_s[LNB * RANK];
    __shared__ __align__(16) float tv_s[LNB * RANK];
    __shared__ __align__(16) float qc_s[LNB * RANK];
    __shared__ __align__(16) float qi_s[LNB * RANK];

    const int tid = threadIdx.x;
    const int n0  = blockIdx.y * LNB;

    if (tid < LNB * RANK) {   // 128 threads: one (ln,d) each
        const float sw = softplus_f(W[n0 * RANK + tid]);
        const float tv = tau[n0 * RANK + tid];
        const float c2 = __builtin_amdgcn_cosf(tv);   // cos(2*pi*tau)
        const float s2 = __builtin_amdgcn_sinf(tv);
        sw_s[tid] = sw;
        tv_s[tid] = tv;
        qc_s[tid] = sw * c2;
        qi_s[tid] = -sw * s2;
    }
    __syncthreads();

    const int a  = blockIdx.x * 256 + tid + 1;        // 1..2048
    const int mm = MLEN - a;                          // 2048..4095
    const float fa = (float)a * (1.0f / (float)MLEN);

    float2 h[RANK];
    #pragma unroll
    for (int d = 0; d < RANK; ++d) h[d] = g_Hft[d * MLEN + a];

    #pragma unroll 1
    for (int ln = 0; ln < LNB; ++ln) {
        const int base = ln * RANK;
        float ar = 0.0f, aw = 0.0f;
        #pragma unroll
        for (int d = 0; d < RANK; ++d) {
            const float tv = tv_s[base + d];
            const float sw = sw_s[base + d];
            const float qc = qc_s[base + d];
            const float qi = qi_s[base + d];
            const float r  = tv * fa;                 // revolutions, [0,1)
            const float c  = __builtin_amdgcn_cosf(r);
            const float s  = __builtin_amdgcn_sinf(r);
            const float tre = fmaf(s, h[d].y, c * h[d].x);
            const float tim = fmaf(c, h[d].y, -s * h[d].x);
            ar = fmaf(sw, tre, ar);
            aw = fmaf(qc, tre, fmaf(qi, tim, aw));
        }
        const int rowbase = (n0 + ln) * MLEN;
        out[rowbase + a]  = ar;
        out[rowbase + mm] = aw;
    }

    // m = 0: V[n,0] = sum_d sw * Hft[d,0].x  (phase = 1, DC bin real)
    if (blockIdx.x == 0 && tid == 0) {
        float h0[RANK];
        #pragma unroll
        for (int d = 0; d < RANK; ++d) h0[d] = g_Hft[d * MLEN].x;
        for (int ln = 0; ln < LNB; ++ln) {
            float v = 0.0f;
            #pragma unroll
            for (int d = 0; d < RANK; ++d) v = fmaf(sw_s[ln * RANK + d], h0[d], v);
            out[(n0 + ln) * MLEN] = v;
        }
    }
}

// Guarded generic fallback (interleaved complex), only used if out_size != N*M.
__global__ __launch_bounds__(256) void mix_generic_kernel(const float* __restrict__ W,
                                                          const float* __restrict__ tau,
                                                          float* __restrict__ out,
                                                          int out_size_floats) {
    __shared__ float sw_s[256];
    __shared__ float tau_s[256];
    const int tid = threadIdx.x;
    const int m   = blockIdx.x * 256 + tid;
    const int n0  = blockIdx.y * 16;
    sw_s[tid]  = softplus_f(W[n0 * RANK + tid]);
    tau_s[tid] = tau[n0 * RANK + tid];
    __syncthreads();
    float2 h[RANK];
    #pragma unroll
    for (int d = 0; d < RANK; ++d) h[d] = g_Hft[d * MLEN + m];
    const float fm = (float)m * (1.0f / (float)MLEN);
    #pragma unroll 1
    for (int ln = 0; ln < 16; ++ln) {
        float ar = 0.0f, ai = 0.0f;
        #pragma unroll
        for (int d = 0; d < RANK; ++d) {
            const float r = tau_s[ln * RANK + d] * fm;
            const float c = __builtin_amdgcn_cosf(r);
            const float s = __builtin_amdgcn_sinf(r);
            const float sw = sw_s[ln * RANK + d];
            ar = fmaf(sw, fmaf(s, h[d].y, c * h[d].x), ar);
            ai = fmaf(sw, fmaf(c, h[d].y, -s * h[d].x), ai);
        }
        const long long fi = 2LL * ((long long)(n0 + ln) * MLEN + m);
        if (fi + 1 < (long long)out_size_floats) {
            out[fi]     = ar;
            out[fi + 1] = ai;
        }
    }
}

extern "C" void kernel_launch(void* const* d_in, const int* in_sizes, int n_in,
                              void* d_out, int out_size, void* d_ws, size_t ws_size,
                              hipStream_t stream) {
    const float* W   = (const float*)d_in[0];   // (1024, 16)
    const float* H   = (const float*)d_in[1];   // (16, 4096)
    const float* tau = (const float*)d_in[2];   // (1024, 16)
    float* out = (float*)d_out;
    (void)d_ws; (void)ws_size; (void)in_sizes; (void)n_in;

    fft_rows_kernel<<<dim3(RANK), dim3(1024), 0, stream>>>(H);

    if (out_size == NROWS * MLEN) {
        // pairs a in [1,2048] -> grid.x = 2048/256 = 8; n-tiles of LNB
        mix_mirror_kernel<<<dim3(8, NROWS / LNB), dim3(256), 0, stream>>>(W, tau, out);
    } else {
        mix_generic_kernel<<<dim3(MLEN / 256, NROWS / 16), dim3(256), 0, stream>>>(
            W, tau, out, out_size);
    }
}